// Round 1
// baseline (184.970 us; speedup 1.0000x reference)
//
#include <hip/hip_runtime.h>
#include <math.h>

typedef __attribute__((ext_vector_type(8))) short short8;
typedef __attribute__((ext_vector_type(4))) float f32x4;
typedef unsigned short ushortT;

#define NB     16
#define CIN    512
#define TT     2048
#define COUT2  1024
#define NSTYLE 128
#define KKTOT  1536      // 3 * 512
#define TPAD   2050      // T + 2 pad rows

// SCALE_LIN = 1/sqrt(128), SCALE_CONV = 1/sqrt(512*9)
#define SCALE_LIN  0.088388347648318447f
#define SCALE_CONV 0.014731391274719736f

__device__ __forceinline__ ushortT f2bf(float f) {
  union { float f; unsigned u; } v; v.f = f;
  unsigned r = v.u + 0x7fffu + ((v.u >> 16) & 1u);
  return (ushortT)(r >> 16);
}

__device__ __forceinline__ void gload16(const void* g, void* l) {
  __builtin_amdgcn_global_load_lds(
      (const __attribute__((address_space(1))) void*)g,
      (__attribute__((address_space(3))) void*)l, 16, 0, 0);
}

// ---------------- s / beta: [16,512] each ----------------
__global__ void style_kernel(const float* __restrict__ c_trg,
                             const float* __restrict__ w_s, const float* __restrict__ b_s,
                             const float* __restrict__ w_b, const float* __restrict__ b_b,
                             float* __restrict__ s, float* __restrict__ beta) {
  int gid = blockIdx.x * 256 + threadIdx.x;   // b*512 + ci
  int b = gid >> 9, ci = gid & 511;
  const float* ct = c_trg + b * NSTYLE;
  const float* ws = w_s + ci * NSTYLE;
  const float* wb = w_b + ci * NSTYLE;
  float as = 0.f, ab = 0.f;
#pragma unroll 8
  for (int j = 0; j < NSTYLE; ++j) {
    float c = ct[j];
    as += c * ws[j];
    ab += c * wb[j];
  }
  s[gid]    = as * SCALE_LIN + b_s[ci];
  beta[gid] = ab * SCALE_LIN + b_b[ci];
}

// ---------------- zero the 2 pad rows of xT ----------------
__global__ void zpad_kernel(ushortT* __restrict__ xT) {
  int i = blockIdx.x * 256 + threadIdx.x;     // 16*2*512 = 16384
  int b = i >> 10; int rest = i & 1023;
  int whichRow = rest >> 9; int ci = rest & 511;
  size_t row = whichRow ? (size_t)(TPAD - 1) : 0;
  xT[((size_t)b * TPAD + row) * CIN + ci] = 0;
}

// ---------------- x [b][ci][t] f32 -> xT [b][t+1][ci] bf16 ----------------
__global__ void xpose_kernel(const float* __restrict__ x, ushortT* __restrict__ xT) {
  int b = blockIdx.z, ctile = blockIdx.y, ttile = blockIdx.x;
  int t0 = ttile * 64, ci0 = ctile * 64;
  __shared__ float tile[64][65];
  int tx = threadIdx.x & 63;
  int ty = threadIdx.x >> 6;                  // 0..3
  const float* xB = x + (size_t)b * CIN * TT;
#pragma unroll
  for (int r = ty; r < 64; r += 4)
    tile[r][tx] = xB[(size_t)(ci0 + r) * TT + t0 + tx];
  __syncthreads();
  ushortT* xTB = xT + (size_t)b * TPAD * CIN;
#pragma unroll
  for (int r = ty; r < 64; r += 4)
    xTB[(size_t)(1 + t0 + r) * CIN + ci0 + tx] = f2bf(tile[tx][r]);
}

// ---------------- modulate + demod-normalize weights -> bf16 ----------------
// wnorm[b][r][kk], r = (co&511)*2 + (co>>9)  (GLU-interleaved rows), kk = k*512+ci
__global__ void modw_kernel(const float* __restrict__ weight,
                            const float* __restrict__ s, const float* __restrict__ beta,
                            ushortT* __restrict__ wnorm) {
  int co = blockIdx.x;           // 0..1023
  int b  = blockIdx.y;           // 0..15
  int tid = threadIdx.x;         // 0..255, 6 elements each
  const float* sB = s + b * CIN;
  const float* bB = beta + b * CIN;
  float wloc[6];
  float sum = 0.f, sq = 0.f;
  int kk0 = tid * 6;
#pragma unroll
  for (int j = 0; j < 6; ++j) {
    int kk = kk0 + j;
    int k = kk >> 9;             // tap
    int ci = kk & 511;
    float wv = weight[((size_t)co * CIN + ci) * 3 + k];
    float val = SCALE_CONV * (wv * sB[ci] + bB[ci]);
    wloc[j] = val;
    sum += val; sq += val * val;
  }
  __shared__ float rs[256], rq[256];
  rs[tid] = sum; rq[tid] = sq;
  __syncthreads();
  for (int off = 128; off > 0; off >>= 1) {
    if (tid < off) { rs[tid] += rs[tid + off]; rq[tid] += rq[tid + off]; }
    __syncthreads();
  }
  float mean  = rs[0] * (1.0f / 1536.0f);
  float demod = rsqrtf(rq[0] + 1e-8f);
  int r = ((co & 511) << 1) | (co >> 9);
  ushortT* dst = wnorm + ((size_t)b * COUT2 + r) * KKTOT + kk0;
#pragma unroll
  for (int j = 0; j < 6; ++j)
    dst[j] = f2bf((wloc[j] - mean) * demod);
}

// ---------------- main conv-as-GEMM with fused GLU ----------------
// C[co'][t] = sum_kk wnorm[b][co'][kk] * xT[b][t + tap(kk)][ci(kk)]
#define BM 128
#define BN 128
#define BK 64

__global__ __launch_bounds__(256, 2)
void conv_gemm(const ushortT* __restrict__ wnorm, const ushortT* __restrict__ xT,
               float* __restrict__ out) {
  int t0  = blockIdx.x * BN;
  int co0 = blockIdx.y * BM;
  int b   = blockIdx.z;
  int tid = threadIdx.x;
  int l = tid & 63;
  int w = tid >> 6;
  int wm = w >> 1, wn = w & 1;

  __shared__ ushortT As[BM * BK];   // [row co'][kk]  (swizzled 16B blocks)
  __shared__ ushortT Bs[BN * BK];   // [row t  ][kk]  (swizzled 16B blocks)

  f32x4 acc[4][4];
#pragma unroll
  for (int i = 0; i < 4; ++i)
#pragma unroll
    for (int j = 0; j < 4; ++j)
      acc[i][j] = (f32x4){0.f, 0.f, 0.f, 0.f};

  const ushortT* wB = wnorm + (size_t)b * COUT2 * KKTOT;
  const ushortT* xB = xT + (size_t)b * TPAD * CIN;

  for (int kb = 0; kb < KKTOT; kb += BK) {
    int ktap = kb >> 9;            // 0,1,2
    int cib  = kb & 511;           // ci base of this chunk
    __syncthreads();
    // stage A and B tiles: 16KB each, 4 wave-issues/tile/wave, pre-swizzled source
#pragma unroll
    for (int q = 0; q < 4; ++q) {
      int n = (w * 4 + q) * 64 + l;       // 16B-block index 0..1023
      int r = n >> 3, jb = n & 7;         // row, block-in-row
      int colsw = ((jb ^ (r & 7)) << 3);  // swizzled element column
      const ushortT* srcA = wB + (size_t)(co0 + r) * KKTOT + kb + colsw;
      gload16(srcA, As + (size_t)(w * 4 + q) * 512);
      const ushortT* srcB = xB + (size_t)(t0 + r + ktap) * CIN + cib + colsw;
      gload16(srcB, Bs + (size_t)(w * 4 + q) * 512);
    }
    __syncthreads();
#pragma unroll
    for (int ks = 0; ks < 2; ++ks) {
      short8 af[4], bfr[4];
#pragma unroll
      for (int mi = 0; mi < 4; ++mi) {
        int ra = wm * 64 + mi * 16 + (l & 15);
        int bc = (ks * 64 + ((l >> 4) << 4)) ^ ((ra & 7) << 4);
        af[mi] = *(const short8*)((const char*)As + ra * 128 + bc);
      }
#pragma unroll
      for (int ni = 0; ni < 4; ++ni) {
        int rb = wn * 64 + ni * 16 + (l & 15);
        int bc = (ks * 64 + ((l >> 4) << 4)) ^ ((rb & 7) << 4);
        bfr[ni] = *(const short8*)((const char*)Bs + rb * 128 + bc);
      }
#pragma unroll
      for (int mi = 0; mi < 4; ++mi)
#pragma unroll
        for (int ni = 0; ni < 4; ++ni)
          acc[mi][ni] = __builtin_amdgcn_mfma_f32_16x16x32_bf16(
              af[mi], bfr[ni], acc[mi][ni], 0, 0, 0);
    }
  }

  // epilogue: rows alternate a/g (interleaved co'); regs (0,1)=(a,g) of channel c,
  // regs (2,3)=(a,g) of channel c+1. GLU: a * sigmoid(g).
#pragma unroll
  for (int mi = 0; mi < 4; ++mi) {
    int cop = co0 + wm * 64 + mi * 16 + ((l >> 4) << 2);  // global co' (mult of 4)
    int c = cop >> 1;
#pragma unroll
    for (int ni = 0; ni < 4; ++ni) {
      int t = t0 + wn * 64 + ni * 16 + (l & 15);
      f32x4 v = acc[mi][ni];
      float o0 = v.x / (1.f + __expf(-v.y));
      float o1 = v.z / (1.f + __expf(-v.w));
      out[((size_t)b * (COUT2 / 2) + c) * TT + t]     = o0;
      out[((size_t)b * (COUT2 / 2) + c + 1) * TT + t] = o1;
    }
  }
}

extern "C" void kernel_launch(void* const* d_in, const int* in_sizes, int n_in,
                              void* d_out, int out_size, void* d_ws, size_t ws_size,
                              hipStream_t stream) {
  const float* x      = (const float*)d_in[0];
  // d_in[1] = c_src  (unused by reference)
  const float* c_trg  = (const float*)d_in[2];
  const float* w_s    = (const float*)d_in[3];
  const float* b_s    = (const float*)d_in[4];
  const float* w_b    = (const float*)d_in[5];
  const float* b_b    = (const float*)d_in[6];
  const float* weight = (const float*)d_in[7];
  float* out = (float*)d_out;

  char* ws = (char*)d_ws;
  float*   s     = (float*)ws;                           // 32 KB
  float*   beta  = (float*)(ws + 32768);                 // 32 KB
  ushortT* xT    = (ushortT*)(ws + 65536);               // 16*2050*512*2 = 33,587,200 B
  ushortT* wnorm = (ushortT*)(ws + 65536 + 33587200);    // 16*1024*1536*2 = 50,331,648 B
  // total ws use: 83,984,384 bytes

  style_kernel<<<32, 256, 0, stream>>>(c_trg, w_s, b_s, w_b, b_b, s, beta);
  zpad_kernel<<<64, 256, 0, stream>>>(xT);
  xpose_kernel<<<dim3(32, 8, 16), 256, 0, stream>>>(x, xT);
  modw_kernel<<<dim3(1024, 16), 256, 0, stream>>>(weight, s, beta, wnorm);
  conv_gemm<<<dim3(16, 8, 16), 256, 0, stream>>>(wnorm, xT, out);
}

// Round 3
// 136.809 us; speedup vs baseline: 1.3520x; 1.3520x over previous
//
#include <hip/hip_runtime.h>
#include <math.h>

typedef __attribute__((ext_vector_type(8))) short short8;
typedef __attribute__((ext_vector_type(4))) float f32x4;
typedef unsigned short ushortT;

#define NB     16
#define CIN    512
#define TT     2048
#define COUT2  1024
#define NSTYLE 128
#define KKTOT  1536      // 3 * 512
#define TPAD   2050      // T + 2 pad rows
#define NKT    24        // K-tiles of 64

#define SCALE_LIN  0.088388347648318447f
#define SCALE_CONV 0.014731391274719736f

__device__ __forceinline__ ushortT f2bf(float f) {
  union { float f; unsigned u; } v; v.f = f;
  unsigned r = v.u + 0x7fffu + ((v.u >> 16) & 1u);
  return (ushortT)(r >> 16);
}

__device__ __forceinline__ void gload16(const void* g, void* l) {
  __builtin_amdgcn_global_load_lds(
      (const __attribute__((address_space(1))) void*)g,
      (__attribute__((address_space(3))) void*)l, 16, 0, 0);
}

// ---------------- s / beta + pad-row zeroing ----------------
__global__ void style_kernel(const float* __restrict__ c_trg,
                             const float* __restrict__ w_s, const float* __restrict__ b_s,
                             const float* __restrict__ w_b, const float* __restrict__ b_b,
                             float* __restrict__ s, float* __restrict__ beta,
                             ushortT* __restrict__ xT) {
  int gid = blockIdx.x * 256 + threadIdx.x;   // 0..8191 = b*512 + ci
  int b = gid >> 9, ci = gid & 511;
  const float* ct = c_trg + b * NSTYLE;
  const float* ws = w_s + ci * NSTYLE;
  const float* wb = w_b + ci * NSTYLE;
  float as = 0.f, ab = 0.f;
#pragma unroll 8
  for (int j = 0; j < NSTYLE; ++j) {
    float c = ct[j];
    as += c * ws[j];
    ab += c * wb[j];
  }
  s[gid]    = as * SCALE_LIN + b_s[ci];
  beta[gid] = ab * SCALE_LIN + b_b[ci];
  // zero the two pad rows of xT (16*2*512 writes, 2 per thread)
  xT[(size_t)b * TPAD * CIN + ci] = 0;
  xT[((size_t)b * TPAD + TPAD - 1) * CIN + ci] = 0;
}

// ---------------- x [b][ci][t] f32 -> xT [b][t+1][ci] bf16 ----------------
__global__ void xpose_kernel(const float* __restrict__ x, ushortT* __restrict__ xT) {
  int b = blockIdx.z, ct = blockIdx.y, tt = blockIdx.x;
  int t0 = tt * 64, ci0 = ct * 64;
  __shared__ float tile[64][65];
  const float* xB = x + (size_t)b * CIN * TT;
  int rr = threadIdx.x >> 4;   // 0..15
  int c4 = threadIdx.x & 15;   // 0..15
#pragma unroll
  for (int it = 0; it < 4; ++it) {
    int ci = rr + it * 16;
    float4 v = *(const float4*)(xB + (size_t)(ci0 + ci) * TT + t0 + c4 * 4);
    tile[ci][c4 * 4 + 0] = v.x; tile[ci][c4 * 4 + 1] = v.y;
    tile[ci][c4 * 4 + 2] = v.z; tile[ci][c4 * 4 + 3] = v.w;
  }
  __syncthreads();
  ushortT* xTB = xT + (size_t)b * TPAD * CIN;
#pragma unroll
  for (int it = 0; it < 4; ++it) {
    int t = rr + it * 16;
    ushort4 o;
    o.x = f2bf(tile[c4 * 4 + 0][t]); o.y = f2bf(tile[c4 * 4 + 1][t]);
    o.z = f2bf(tile[c4 * 4 + 2][t]); o.w = f2bf(tile[c4 * 4 + 3][t]);
    *(ushort4*)(xTB + (size_t)(1 + t0 + t) * CIN + ci0 + c4 * 4) = o;
  }
}

// ---------------- modulate + demod-normalize weights -> bf16 ----------------
// wnorm[b][r][kk], r = (co&511)*2 | (co>>9)  (GLU-interleaved rows), kk = k*512+ci
__global__ void modw_kernel(const float* __restrict__ weight,
                            const float* __restrict__ s, const float* __restrict__ beta,
                            ushortT* __restrict__ wnorm) {
  int co = blockIdx.x, b = blockIdx.y, tid = threadIdx.x;  // 256 threads, 2 ci each
  int ci = tid * 2;
  const float* wp = weight + (size_t)co * CIN * 3 + (size_t)ci * 3;  // 6 contiguous floats
  float s0 = s[b * CIN + ci],     s1 = s[b * CIN + ci + 1];
  float e0 = beta[b * CIN + ci],  e1 = beta[b * CIN + ci + 1];
  float w0 = SCALE_CONV * (wp[0] * s0 + e0);
  float w1 = SCALE_CONV * (wp[1] * s0 + e0);
  float w2 = SCALE_CONV * (wp[2] * s0 + e0);
  float w3 = SCALE_CONV * (wp[3] * s1 + e1);
  float w4 = SCALE_CONV * (wp[4] * s1 + e1);
  float w5 = SCALE_CONV * (wp[5] * s1 + e1);
  float sum = w0 + w1 + w2 + w3 + w4 + w5;
  float sq  = w0*w0 + w1*w1 + w2*w2 + w3*w3 + w4*w4 + w5*w5;
#pragma unroll
  for (int off = 32; off; off >>= 1) {
    sum += __shfl_xor(sum, off);
    sq  += __shfl_xor(sq,  off);
  }
  __shared__ float rs[4], rq[4];
  if ((tid & 63) == 0) { rs[tid >> 6] = sum; rq[tid >> 6] = sq; }
  __syncthreads();
  float tsum = rs[0] + rs[1] + rs[2] + rs[3];
  float tsq  = rq[0] + rq[1] + rq[2] + rq[3];
  float mean  = tsum * (1.0f / 1536.0f);
  float demod = rsqrtf(tsq + 1e-8f);
  int r = ((co & 511) << 1) | (co >> 9);
  ushortT* dst = wnorm + ((size_t)b * COUT2 + r) * KKTOT;
  ushort2 p0, p1, p2;
  p0.x = f2bf((w0 - mean) * demod); p0.y = f2bf((w3 - mean) * demod);
  p1.x = f2bf((w1 - mean) * demod); p1.y = f2bf((w4 - mean) * demod);
  p2.x = f2bf((w2 - mean) * demod); p2.y = f2bf((w5 - mean) * demod);
  *(ushort2*)(dst +        ci) = p0;
  *(ushort2*)(dst +  512 + ci) = p1;
  *(ushort2*)(dst + 1024 + ci) = p2;
}

// ---------------- main conv-as-GEMM: 256^2 tile, 8-phase pipeline ----------------
// LDS regions: ridx = ((dbuf*2 + op)*2 + ks), region = [256 rows][32 cols] bf16
// = 8192 elements = 16384 bytes. Rows 64B = 4x16B blocks XOR-swizzled by (row>>1)&3.
// Total 8 regions = 128 KiB.

#define AFRAG(d, s, f) (*(const short8*)(ldsc + ((d) * 4 + (s)) * 16384 + aoff + (f) * 1024))
#define BFRAG(d, s, g) (*(const short8*)(ldsc + ((d) * 4 + 2 + (s)) * 16384 + boff + (g) * 1024))

#define STAGE_A(d, s, kt) do {                                                   \
    int kc_ = (kt) * 64 + (s) * 32;                                              \
    gload16(wB + (size_t)(co0 + r0) * KKTOT + kc_ + jbs8,                        \
            ldsw + ((d) * 4 + (s)) * 8192 + tid * 8);                            \
    gload16(wB + (size_t)(co0 + r0 + 128) * KKTOT + kc_ + jbs8,                  \
            ldsw + ((d) * 4 + (s)) * 8192 + 4096 + tid * 8);                     \
  } while (0)

#define STAGE_B(d, s, kt) do {                                                   \
    int kc_ = (kt) * 64 + (s) * 32;                                              \
    int tap_ = kc_ >> 9; int ci_ = kc_ & 511;                                    \
    gload16(xB + (size_t)(t0 + r0 + tap_) * CIN + ci_ + jbs8,                    \
            ldsw + ((d) * 4 + 2 + (s)) * 8192 + tid * 8);                        \
    gload16(xB + (size_t)(t0 + r0 + 128 + tap_) * CIN + ci_ + jbs8,              \
            ldsw + ((d) * 4 + 2 + (s)) * 8192 + 4096 + tid * 8);                 \
  } while (0)

// VMN: 6 -> vmcnt(6), 0 -> vmcnt(0), -1 -> none
#define PHASE(d, s, mh, STAGES, VMN) do {                                        \
    short8 a0 = AFRAG(d, s, (mh) * 4 + 0);                                       \
    short8 a1 = AFRAG(d, s, (mh) * 4 + 1);                                       \
    short8 a2 = AFRAG(d, s, (mh) * 4 + 2);                                       \
    short8 a3 = AFRAG(d, s, (mh) * 4 + 3);                                       \
    if ((mh) == 0) {                                                             \
      bf0 = BFRAG(d, s, 0); bf1 = BFRAG(d, s, 1);                                \
      bf2 = BFRAG(d, s, 2); bf3 = BFRAG(d, s, 3);                                \
    }                                                                            \
    STAGES;                                                                      \
    if ((VMN) == 6)      asm volatile("s_waitcnt vmcnt(6)" ::: "memory");        \
    else if ((VMN) == 0) asm volatile("s_waitcnt vmcnt(0)" ::: "memory");        \
    __builtin_amdgcn_sched_barrier(0);                                           \
    __builtin_amdgcn_s_barrier();                                                \
    __builtin_amdgcn_sched_barrier(0);                                           \
    __builtin_amdgcn_s_setprio(1);                                               \
    acc[(mh)*4+0][0] = __builtin_amdgcn_mfma_f32_16x16x32_bf16(a0, bf0, acc[(mh)*4+0][0], 0, 0, 0); \
    acc[(mh)*4+0][1] = __builtin_amdgcn_mfma_f32_16x16x32_bf16(a0, bf1, acc[(mh)*4+0][1], 0, 0, 0); \
    acc[(mh)*4+0][2] = __builtin_amdgcn_mfma_f32_16x16x32_bf16(a0, bf2, acc[(mh)*4+0][2], 0, 0, 0); \
    acc[(mh)*4+0][3] = __builtin_amdgcn_mfma_f32_16x16x32_bf16(a0, bf3, acc[(mh)*4+0][3], 0, 0, 0); \
    acc[(mh)*4+1][0] = __builtin_amdgcn_mfma_f32_16x16x32_bf16(a1, bf0, acc[(mh)*4+1][0], 0, 0, 0); \
    acc[(mh)*4+1][1] = __builtin_amdgcn_mfma_f32_16x16x32_bf16(a1, bf1, acc[(mh)*4+1][1], 0, 0, 0); \
    acc[(mh)*4+1][2] = __builtin_amdgcn_mfma_f32_16x16x32_bf16(a1, bf2, acc[(mh)*4+1][2], 0, 0, 0); \
    acc[(mh)*4+1][3] = __builtin_amdgcn_mfma_f32_16x16x32_bf16(a1, bf3, acc[(mh)*4+1][3], 0, 0, 0); \
    acc[(mh)*4+2][0] = __builtin_amdgcn_mfma_f32_16x16x32_bf16(a2, bf0, acc[(mh)*4+2][0], 0, 0, 0); \
    acc[(mh)*4+2][1] = __builtin_amdgcn_mfma_f32_16x16x32_bf16(a2, bf1, acc[(mh)*4+2][1], 0, 0, 0); \
    acc[(mh)*4+2][2] = __builtin_amdgcn_mfma_f32_16x16x32_bf16(a2, bf2, acc[(mh)*4+2][2], 0, 0, 0); \
    acc[(mh)*4+2][3] = __builtin_amdgcn_mfma_f32_16x16x32_bf16(a2, bf3, acc[(mh)*4+2][3], 0, 0, 0); \
    acc[(mh)*4+3][0] = __builtin_amdgcn_mfma_f32_16x16x32_bf16(a3, bf0, acc[(mh)*4+3][0], 0, 0, 0); \
    acc[(mh)*4+3][1] = __builtin_amdgcn_mfma_f32_16x16x32_bf16(a3, bf1, acc[(mh)*4+3][1], 0, 0, 0); \
    acc[(mh)*4+3][2] = __builtin_amdgcn_mfma_f32_16x16x32_bf16(a3, bf2, acc[(mh)*4+3][2], 0, 0, 0); \
    acc[(mh)*4+3][3] = __builtin_amdgcn_mfma_f32_16x16x32_bf16(a3, bf3, acc[(mh)*4+3][3], 0, 0, 0); \
    __builtin_amdgcn_s_setprio(0);                                               \
    __builtin_amdgcn_sched_barrier(0);                                           \
    __builtin_amdgcn_s_barrier();                                                \
    __builtin_amdgcn_sched_barrier(0);                                           \
  } while (0)

__global__ __launch_bounds__(512, 2)
void conv_gemm8(const ushortT* __restrict__ wnorm, const ushortT* __restrict__ xT,
                float* __restrict__ out) {
  extern __shared__ ushortT ldsw[];
  const char* ldsc = (const char*)ldsw;

  // XCD-chunked bijective swizzle (512 blocks % 8 == 0)
  int orig = blockIdx.x;
  int wgid = (orig & 7) * 64 + (orig >> 3);
  int b  = wgid >> 5;
  int i5 = wgid & 31;
  int mp = i5 >> 4, r2 = i5 & 15;
  int nt = r2 >> 1, mt = mp * 2 + (r2 & 1);
  int co0 = mt * 256, t0 = nt * 256;

  int tid = threadIdx.x;
  int l = tid & 63, w = tid >> 6;
  int wm = w & 1, wn = w >> 1;           // 2 x 4 wave grid

  // staging constants: r0 = row (0..127) of issue q=0, jbs8 = swizzled col offset
  int r0 = tid >> 2;
  int jbs8 = (((tid & 3) ^ ((r0 >> 1) & 3)) << 3);
  // ds_read constants
  int cb = ((l >> 4) ^ ((l >> 1) & 3));
  int aoff = (wm * 128 + (l & 15)) * 64 + cb * 16;
  int boff = (wn * 64  + (l & 15)) * 64 + cb * 16;

  const ushortT* wB = wnorm + (size_t)b * COUT2 * KKTOT;
  const ushortT* xB = xT + (size_t)b * TPAD * CIN;

  f32x4 acc[8][4];
#pragma unroll
  for (int i = 0; i < 8; ++i)
#pragma unroll
    for (int j = 0; j < 4; ++j)
      acc[i][j] = (f32x4){0.f, 0.f, 0.f, 0.f};
  short8 bf0 = {}, bf1 = {}, bf2 = {}, bf3 = {};

  // prologue: kt0 all 4 halves, then kt1 {B-ks0, A-ks0, B-ks1}
  STAGE_A(0, 0, 0); STAGE_B(0, 0, 0); STAGE_A(0, 1, 0); STAGE_B(0, 1, 0);
  STAGE_B(1, 0, 1); STAGE_A(1, 0, 1); STAGE_B(1, 1, 1);
  asm volatile("s_waitcnt vmcnt(6)" ::: "memory");
  __builtin_amdgcn_sched_barrier(0);
  __builtin_amdgcn_s_barrier();
  __builtin_amdgcn_sched_barrier(0);

  for (int j = 0; j < 11; ++j) {
    int kt1 = 2 * j + 1;
    int ktn0 = 2 * j + 2, ktn1 = 2 * j + 3;
    PHASE(0, 0, 0, STAGE_A(1, 1, kt1),  -1);
    PHASE(0, 0, 1, STAGE_B(0, 0, ktn0), -1);
    PHASE(0, 1, 0, STAGE_A(0, 0, ktn0), -1);
    PHASE(0, 1, 1, STAGE_B(0, 1, ktn0),  6);
    PHASE(1, 0, 0, STAGE_A(0, 1, ktn0), -1);
    PHASE(1, 0, 1, STAGE_B(1, 0, ktn1), -1);
    PHASE(1, 1, 0, STAGE_A(1, 0, ktn1), -1);
    PHASE(1, 1, 1, STAGE_B(1, 1, ktn1),  6);
  }
  // peeled final iteration (kt0=22, kt1=23): only ph1 stages; drain at ph4
  PHASE(0, 0, 0, STAGE_A(1, 1, 23), -1);
  PHASE(0, 0, 1, {}, -1);
  PHASE(0, 1, 0, {}, -1);
  PHASE(0, 1, 1, {},  0);
  PHASE(1, 0, 0, {}, -1);
  PHASE(1, 0, 1, {}, -1);
  PHASE(1, 1, 0, {}, -1);
  PHASE(1, 1, 1, {}, -1);

  // epilogue: rows are GLU-interleaved co'; regs (x,y)/(z,w) = (a,g) channel pairs
#pragma unroll
  for (int f = 0; f < 8; ++f) {
    int cop = co0 + wm * 128 + f * 16 + ((l >> 4) << 2);
    int c = cop >> 1;
    size_t obase = ((size_t)b * (COUT2 / 2) + c) * TT;
#pragma unroll
    for (int g = 0; g < 4; ++g) {
      int t = t0 + wn * 64 + g * 16 + (l & 15);
      f32x4 v = acc[f][g];
      out[obase + t]      = v.x / (1.f + __expf(-v.y));
      out[obase + TT + t] = v.z / (1.f + __expf(-v.w));
    }
  }
}

extern "C" void kernel_launch(void* const* d_in, const int* in_sizes, int n_in,
                              void* d_out, int out_size, void* d_ws, size_t ws_size,
                              hipStream_t stream) {
  const float* x      = (const float*)d_in[0];
  const float* c_trg  = (const float*)d_in[2];
  const float* w_s    = (const float*)d_in[3];
  const float* b_s    = (const float*)d_in[4];
  const float* w_b    = (const float*)d_in[5];
  const float* b_b    = (const float*)d_in[6];
  const float* weight = (const float*)d_in[7];
  float* out = (float*)d_out;

  char* ws = (char*)d_ws;
  float*   s     = (float*)ws;                           // 32 KB
  float*   beta  = (float*)(ws + 32768);                 // 32 KB
  ushortT* xT    = (ushortT*)(ws + 65536);               // 33,587,200 B
  ushortT* wnorm = (ushortT*)(ws + 65536 + 33587200);    // 50,331,648 B

  hipFuncSetAttribute((const void*)conv_gemm8,
                      hipFuncAttributeMaxDynamicSharedMemorySize, 131072);

  style_kernel<<<32, 256, 0, stream>>>(c_trg, w_s, b_s, w_b, b_b, s, beta, xT);
  xpose_kernel<<<dim3(32, 8, 16), 256, 0, stream>>>(x, xT);
  modw_kernel<<<dim3(1024, 16), 256, 0, stream>>>(weight, s, beta, wnorm);
  conv_gemm8<<<512, 512, 131072, stream>>>(wnorm, xT, out);
}

// Round 4
// 136.358 us; speedup vs baseline: 1.3565x; 1.0033x over previous
//
#include <hip/hip_runtime.h>
#include <math.h>

typedef __attribute__((ext_vector_type(8))) short short8;
typedef __attribute__((ext_vector_type(4))) float f32x4;
typedef unsigned short ushortT;

#define NB     16
#define CIN    512
#define TT     2048
#define COUT2  1024
#define NSTYLE 128
#define KKTOT  1536      // 3 * 512
#define TPAD   2050      // T + 2 pad rows
#define NKT    24        // K-tiles of 64

#define SCALE_LIN  0.088388347648318447f
#define SCALE_CONV 0.014731391274719736f

__device__ __forceinline__ ushortT f2bf(float f) {
  union { float f; unsigned u; } v; v.f = f;
  unsigned r = v.u + 0x7fffu + ((v.u >> 16) & 1u);
  return (ushortT)(r >> 16);
}

__device__ __forceinline__ void gload16(const void* g, void* l) {
  __builtin_amdgcn_global_load_lds(
      (const __attribute__((address_space(1))) void*)g,
      (__attribute__((address_space(3))) void*)l, 16, 0, 0);
}

// ---------------- s / beta + pad-row zeroing ----------------
__global__ void style_kernel(const float* __restrict__ c_trg,
                             const float* __restrict__ w_s, const float* __restrict__ b_s,
                             const float* __restrict__ w_b, const float* __restrict__ b_b,
                             float* __restrict__ s, float* __restrict__ beta,
                             ushortT* __restrict__ xT) {
  int gid = blockIdx.x * 256 + threadIdx.x;   // 0..8191 = b*512 + ci
  int b = gid >> 9, ci = gid & 511;
  const float* ct = c_trg + b * NSTYLE;
  const float* ws = w_s + ci * NSTYLE;
  const float* wb = w_b + ci * NSTYLE;
  float as = 0.f, ab = 0.f;
#pragma unroll 8
  for (int j = 0; j < NSTYLE; ++j) {
    float c = ct[j];
    as += c * ws[j];
    ab += c * wb[j];
  }
  s[gid]    = as * SCALE_LIN + b_s[ci];
  beta[gid] = ab * SCALE_LIN + b_b[ci];
  xT[(size_t)b * TPAD * CIN + ci] = 0;
  xT[((size_t)b * TPAD + TPAD - 1) * CIN + ci] = 0;
}

// ---------------- x [b][ci][t] f32 -> xT [b][t+1][ci] bf16 ----------------
__global__ void xpose_kernel(const float* __restrict__ x, ushortT* __restrict__ xT) {
  int b = blockIdx.z, ct = blockIdx.y, tt = blockIdx.x;
  int t0 = tt * 64, ci0 = ct * 64;
  __shared__ float tile[64][65];
  const float* xB = x + (size_t)b * CIN * TT;
  int rr = threadIdx.x >> 4;   // 0..15
  int c4 = threadIdx.x & 15;   // 0..15
#pragma unroll
  for (int it = 0; it < 4; ++it) {
    int ci = rr + it * 16;
    float4 v = *(const float4*)(xB + (size_t)(ci0 + ci) * TT + t0 + c4 * 4);
    tile[ci][c4 * 4 + 0] = v.x; tile[ci][c4 * 4 + 1] = v.y;
    tile[ci][c4 * 4 + 2] = v.z; tile[ci][c4 * 4 + 3] = v.w;
  }
  __syncthreads();
  ushortT* xTB = xT + (size_t)b * TPAD * CIN;
#pragma unroll
  for (int it = 0; it < 4; ++it) {
    int t = rr + it * 16;
    ushort4 o;
    o.x = f2bf(tile[c4 * 4 + 0][t]); o.y = f2bf(tile[c4 * 4 + 1][t]);
    o.z = f2bf(tile[c4 * 4 + 2][t]); o.w = f2bf(tile[c4 * 4 + 3][t]);
    *(ushort4*)(xTB + (size_t)(1 + t0 + t) * CIN + ci0 + c4 * 4) = o;
  }
}

// ---------------- modulate + demod-normalize weights -> bf16 ----------------
__global__ void modw_kernel(const float* __restrict__ weight,
                            const float* __restrict__ s, const float* __restrict__ beta,
                            ushortT* __restrict__ wnorm) {
  int co = blockIdx.x, b = blockIdx.y, tid = threadIdx.x;  // 256 threads, 2 ci each
  int ci = tid * 2;
  const float* wp = weight + (size_t)co * CIN * 3 + (size_t)ci * 3;
  float s0 = s[b * CIN + ci],     s1 = s[b * CIN + ci + 1];
  float e0 = beta[b * CIN + ci],  e1 = beta[b * CIN + ci + 1];
  float w0 = SCALE_CONV * (wp[0] * s0 + e0);
  float w1 = SCALE_CONV * (wp[1] * s0 + e0);
  float w2 = SCALE_CONV * (wp[2] * s0 + e0);
  float w3 = SCALE_CONV * (wp[3] * s1 + e1);
  float w4 = SCALE_CONV * (wp[4] * s1 + e1);
  float w5 = SCALE_CONV * (wp[5] * s1 + e1);
  float sum = w0 + w1 + w2 + w3 + w4 + w5;
  float sq  = w0*w0 + w1*w1 + w2*w2 + w3*w3 + w4*w4 + w5*w5;
#pragma unroll
  for (int off = 32; off; off >>= 1) {
    sum += __shfl_xor(sum, off);
    sq  += __shfl_xor(sq,  off);
  }
  __shared__ float rs[4], rq[4];
  if ((tid & 63) == 0) { rs[tid >> 6] = sum; rq[tid >> 6] = sq; }
  __syncthreads();
  float tsum = rs[0] + rs[1] + rs[2] + rs[3];
  float tsq  = rq[0] + rq[1] + rq[2] + rq[3];
  float mean  = tsum * (1.0f / 1536.0f);
  float demod = rsqrtf(tsq + 1e-8f);
  int r = ((co & 511) << 1) | (co >> 9);
  ushortT* dst = wnorm + ((size_t)b * COUT2 + r) * KKTOT;
  ushort2 p0, p1, p2;
  p0.x = f2bf((w0 - mean) * demod); p0.y = f2bf((w3 - mean) * demod);
  p1.x = f2bf((w1 - mean) * demod); p1.y = f2bf((w4 - mean) * demod);
  p2.x = f2bf((w2 - mean) * demod); p2.y = f2bf((w5 - mean) * demod);
  *(ushort2*)(dst +        ci) = p0;
  *(ushort2*)(dst +  512 + ci) = p1;
  *(ushort2*)(dst + 1024 + ci) = p2;
}

// ---------------- main conv-as-GEMM: 256^2 tile, 8-phase, read-ahead regs ----------------
// LDS regions: ridx = ((dbuf*2 + op)*2 + ks), region = [256 rows][32 cols] bf16
// = 16384 bytes. Rows 64B = 4x16B blocks XOR-swizzled by (row>>1)&3. 8 regions = 128 KiB.

#define AFRAG(d, s, f) (*(const short8*)(ldsc + ((d) * 4 + (s)) * 16384 + aoff + (f) * 1024))
#define BFRAG(d, s, g) (*(const short8*)(ldsc + ((d) * 4 + 2 + (s)) * 16384 + boff + (g) * 1024))

// read next-phase A frags (mh half) into set 'as_'
#define RDA(as_, d, s, mh) do {              \
    as_##0 = AFRAG(d, s, (mh) * 4 + 0);      \
    as_##1 = AFRAG(d, s, (mh) * 4 + 1);      \
    as_##2 = AFRAG(d, s, (mh) * 4 + 2);      \
    as_##3 = AFRAG(d, s, (mh) * 4 + 3);      \
  } while (0)

// read next-(d,s) B frags into set 'bs_'
#define RDB(bs_, d, s) do {                  \
    bs_##0 = BFRAG(d, s, 0);                 \
    bs_##1 = BFRAG(d, s, 1);                 \
    bs_##2 = BFRAG(d, s, 2);                 \
    bs_##3 = BFRAG(d, s, 3);                 \
  } while (0)

#define STAGE_A(d, s, kt) do {                                                   \
    int kc_ = (kt) * 64 + (s) * 32;                                              \
    gload16(wB + (size_t)(co0 + r0) * KKTOT + kc_ + jbs8,                        \
            ldsw + ((d) * 4 + (s)) * 8192 + tid * 8);                            \
    gload16(wB + (size_t)(co0 + r0 + 128) * KKTOT + kc_ + jbs8,                  \
            ldsw + ((d) * 4 + (s)) * 8192 + 4096 + tid * 8);                     \
  } while (0)

#define STAGE_B(d, s, kt) do {                                                   \
    int kc_ = (kt) * 64 + (s) * 32;                                              \
    int tap_ = kc_ >> 9; int ci_ = kc_ & 511;                                    \
    gload16(xB + (size_t)(t0 + r0 + tap_) * CIN + ci_ + jbs8,                    \
            ldsw + ((d) * 4 + 2 + (s)) * 8192 + tid * 8);                        \
    gload16(xB + (size_t)(t0 + r0 + 128 + tap_) * CIN + ci_ + jbs8,              \
            ldsw + ((d) * 4 + 2 + (s)) * 8192 + 4096 + tid * 8);                 \
  } while (0)

// PHASE: [reads for NEXT phase][stage][barrier][MFMA on CUR sets][endvm][barrier]
// ENDVM: -1 none, 8 -> vmcnt(8), 0 -> vmcnt(0)   (before the post-MFMA barrier)
#define PHASE(mh, au_, bu_, RD_CODE, STAGES, ENDVM) do {                         \
    RD_CODE;                                                                     \
    STAGES;                                                                      \
    __builtin_amdgcn_sched_barrier(0);                                           \
    __builtin_amdgcn_s_barrier();                                                \
    __builtin_amdgcn_sched_barrier(0);                                           \
    __builtin_amdgcn_s_setprio(1);                                               \
    acc[(mh)*4+0][0] = __builtin_amdgcn_mfma_f32_16x16x32_bf16(au_##0, bu_##0, acc[(mh)*4+0][0], 0, 0, 0); \
    acc[(mh)*4+0][1] = __builtin_amdgcn_mfma_f32_16x16x32_bf16(au_##0, bu_##1, acc[(mh)*4+0][1], 0, 0, 0); \
    acc[(mh)*4+0][2] = __builtin_amdgcn_mfma_f32_16x16x32_bf16(au_##0, bu_##2, acc[(mh)*4+0][2], 0, 0, 0); \
    acc[(mh)*4+0][3] = __builtin_amdgcn_mfma_f32_16x16x32_bf16(au_##0, bu_##3, acc[(mh)*4+0][3], 0, 0, 0); \
    acc[(mh)*4+1][0] = __builtin_amdgcn_mfma_f32_16x16x32_bf16(au_##1, bu_##0, acc[(mh)*4+1][0], 0, 0, 0); \
    acc[(mh)*4+1][1] = __builtin_amdgcn_mfma_f32_16x16x32_bf16(au_##1, bu_##1, acc[(mh)*4+1][1], 0, 0, 0); \
    acc[(mh)*4+1][2] = __builtin_amdgcn_mfma_f32_16x16x32_bf16(au_##1, bu_##2, acc[(mh)*4+1][2], 0, 0, 0); \
    acc[(mh)*4+1][3] = __builtin_amdgcn_mfma_f32_16x16x32_bf16(au_##1, bu_##3, acc[(mh)*4+1][3], 0, 0, 0); \
    acc[(mh)*4+2][0] = __builtin_amdgcn_mfma_f32_16x16x32_bf16(au_##2, bu_##0, acc[(mh)*4+2][0], 0, 0, 0); \
    acc[(mh)*4+2][1] = __builtin_amdgcn_mfma_f32_16x16x32_bf16(au_##2, bu_##1, acc[(mh)*4+2][1], 0, 0, 0); \
    acc[(mh)*4+2][2] = __builtin_amdgcn_mfma_f32_16x16x32_bf16(au_##2, bu_##2, acc[(mh)*4+2][2], 0, 0, 0); \
    acc[(mh)*4+2][3] = __builtin_amdgcn_mfma_f32_16x16x32_bf16(au_##2, bu_##3, acc[(mh)*4+2][3], 0, 0, 0); \
    acc[(mh)*4+3][0] = __builtin_amdgcn_mfma_f32_16x16x32_bf16(au_##3, bu_##0, acc[(mh)*4+3][0], 0, 0, 0); \
    acc[(mh)*4+3][1] = __builtin_amdgcn_mfma_f32_16x16x32_bf16(au_##3, bu_##1, acc[(mh)*4+3][1], 0, 0, 0); \
    acc[(mh)*4+3][2] = __builtin_amdgcn_mfma_f32_16x16x32_bf16(au_##3, bu_##2, acc[(mh)*4+3][2], 0, 0, 0); \
    acc[(mh)*4+3][3] = __builtin_amdgcn_mfma_f32_16x16x32_bf16(au_##3, bu_##3, acc[(mh)*4+3][3], 0, 0, 0); \
    __builtin_amdgcn_s_setprio(0);                                               \
    __builtin_amdgcn_sched_barrier(0);                                           \
    if ((ENDVM) == 8)      asm volatile("s_waitcnt vmcnt(8)" ::: "memory");      \
    else if ((ENDVM) == 0) asm volatile("s_waitcnt vmcnt(0)" ::: "memory");      \
    __builtin_amdgcn_s_barrier();                                                \
    __builtin_amdgcn_sched_barrier(0);                                           \
  } while (0)

__global__ __launch_bounds__(512, 2)
void conv_gemm8(const ushortT* __restrict__ wnorm, const ushortT* __restrict__ xT,
                float* __restrict__ out) {
  extern __shared__ ushortT ldsw[];
  const char* ldsc = (const char*)ldsw;

  // XCD-chunked bijective swizzle (512 blocks % 8 == 0)
  int orig = blockIdx.x;
  int wgid = (orig & 7) * 64 + (orig >> 3);
  int b  = wgid >> 5;
  int i5 = wgid & 31;
  int mp = i5 >> 4, r2 = i5 & 15;
  int nt = r2 >> 1, mt = mp * 2 + (r2 & 1);
  int co0 = mt * 256, t0 = nt * 256;

  int tid = threadIdx.x;
  int l = tid & 63, w = tid >> 6;
  int wm = w & 1, wn = w >> 1;           // 2 x 4 wave grid

  int r0 = tid >> 2;
  int jbs8 = (((tid & 3) ^ ((r0 >> 1) & 3)) << 3);
  int cb = ((l >> 4) ^ ((l >> 1) & 3));
  int aoff = (wm * 128 + (l & 15)) * 64 + cb * 16;
  int boff = (wn * 64  + (l & 15)) * 64 + cb * 16;

  const ushortT* wB = wnorm + (size_t)b * COUT2 * KKTOT;
  const ushortT* xB = xT + (size_t)b * TPAD * CIN;

  f32x4 acc[8][4];
#pragma unroll
  for (int i = 0; i < 8; ++i)
#pragma unroll
    for (int j = 0; j < 4; ++j)
      acc[i][j] = (f32x4){0.f, 0.f, 0.f, 0.f};
  short8 ax0 = {}, ax1 = {}, ax2 = {}, ax3 = {};
  short8 ay0 = {}, ay1 = {}, ay2 = {}, ay3 = {};
  short8 bx0 = {}, bx1 = {}, bx2 = {}, bx3 = {};
  short8 by0 = {}, by1 = {}, by2 = {}, by3 = {};

  // prologue: kt0 all 4 halves, then kt1 {B-ks0, A-ks0, B-ks1}
  STAGE_A(0, 0, 0); STAGE_B(0, 0, 0); STAGE_A(0, 1, 0); STAGE_B(0, 1, 0);
  STAGE_B(1, 0, 1); STAGE_A(1, 0, 1); STAGE_B(1, 1, 1);
  asm volatile("s_waitcnt vmcnt(6)" ::: "memory");
  __builtin_amdgcn_sched_barrier(0);
  __builtin_amdgcn_s_barrier();
  __builtin_amdgcn_sched_barrier(0);
  // initial fragment reads for ph1 (0,0,mh0)
  RDA(ax, 0, 0, 0);
  RDB(bx, 0, 0);

  for (int j = 0; j < 11; ++j) {
    int kt1 = 2 * j + 1;
    int ktn0 = 2 * j + 2, ktn1 = 2 * j + 3;
    PHASE(0, ax, bx, { RDA(ay, 0, 0, 1); },                  STAGE_A(1, 1, kt1),   8);
    PHASE(1, ay, bx, { RDA(ax, 0, 1, 0); RDB(by, 0, 1); },   STAGE_B(0, 0, ktn0), -1);
    PHASE(0, ax, by, { RDA(ay, 0, 1, 1); },                  STAGE_A(0, 0, ktn0),  8);
    PHASE(1, ay, by, { RDA(ax, 1, 0, 0); RDB(bx, 1, 0); },   STAGE_B(0, 1, ktn0), -1);
    PHASE(0, ax, bx, { RDA(ay, 1, 0, 1); },                  STAGE_A(0, 1, ktn0),  8);
    PHASE(1, ay, bx, { RDA(ax, 1, 1, 0); RDB(by, 1, 1); },   STAGE_B(1, 0, ktn1), -1);
    PHASE(0, ax, by, { RDA(ay, 1, 1, 1); },                  STAGE_A(1, 0, ktn1),  8);
    PHASE(1, ay, by, { RDA(ax, 0, 0, 0); RDB(bx, 0, 0); },   STAGE_B(1, 1, ktn1), -1);
  }
  // peeled final iteration (kt 22 in dbuf0 staged last iter, kt 23 in dbuf1):
  // only A(1,1,23) left to stage; vmcnt(0) once at ph1-end covers all later reads.
  PHASE(0, ax, bx, { RDA(ay, 0, 0, 1); },                  STAGE_A(1, 1, 23),     0);
  PHASE(1, ay, bx, { RDA(ax, 0, 1, 0); RDB(by, 0, 1); },   {},                   -1);
  PHASE(0, ax, by, { RDA(ay, 0, 1, 1); },                  {},                   -1);
  PHASE(1, ay, by, { RDA(ax, 1, 0, 0); RDB(bx, 1, 0); },   {},                   -1);
  PHASE(0, ax, bx, { RDA(ay, 1, 0, 1); },                  {},                   -1);
  PHASE(1, ay, bx, { RDA(ax, 1, 1, 0); RDB(by, 1, 1); },   {},                   -1);
  PHASE(0, ax, by, { RDA(ay, 1, 1, 1); },                  {},                   -1);
  PHASE(1, ay, by, { },                                    {},                   -1);

  // epilogue: rows are GLU-interleaved co'; regs (x,y)/(z,w) = (a,g) channel pairs
#pragma unroll
  for (int f = 0; f < 8; ++f) {
    int cop = co0 + wm * 128 + f * 16 + ((l >> 4) << 2);
    int c = cop >> 1;
    size_t obase = ((size_t)b * (COUT2 / 2) + c) * TT;
#pragma unroll
    for (int g = 0; g < 4; ++g) {
      int t = t0 + wn * 64 + g * 16 + (l & 15);
      f32x4 v = acc[f][g];
      out[obase + t]      = v.x / (1.f + __expf(-v.y));
      out[obase + TT + t] = v.z / (1.f + __expf(-v.w));
    }
  }
}

extern "C" void kernel_launch(void* const* d_in, const int* in_sizes, int n_in,
                              void* d_out, int out_size, void* d_ws, size_t ws_size,
                              hipStream_t stream) {
  const float* x      = (const float*)d_in[0];
  const float* c_trg  = (const float*)d_in[2];
  const float* w_s    = (const float*)d_in[3];
  const float* b_s    = (const float*)d_in[4];
  const float* w_b    = (const float*)d_in[5];
  const float* b_b    = (const float*)d_in[6];
  const float* weight = (const float*)d_in[7];
  float* out = (float*)d_out;

  char* ws = (char*)d_ws;
  float*   s     = (float*)ws;                           // 32 KB
  float*   beta  = (float*)(ws + 32768);                 // 32 KB
  ushortT* xT    = (ushortT*)(ws + 65536);               // 33,587,200 B
  ushortT* wnorm = (ushortT*)(ws + 65536 + 33587200);    // 50,331,648 B

  hipFuncSetAttribute((const void*)conv_gemm8,
                      hipFuncAttributeMaxDynamicSharedMemorySize, 131072);

  style_kernel<<<32, 256, 0, stream>>>(c_trg, w_s, b_s, w_b, b_b, s, beta, xT);
  xpose_kernel<<<dim3(32, 8, 16), 256, 0, stream>>>(x, xT);
  modw_kernel<<<dim3(1024, 16), 256, 0, stream>>>(weight, s, beta, wnorm);
  conv_gemm8<<<512, 512, 131072, stream>>>(wnorm, xT, out);
}